// Round 10
// baseline (305.385 us; speedup 1.0000x reference)
//
#include <hip/hip_runtime.h>
#include <hip/hip_bf16.h>
#include <hip/hip_cooperative_groups.h>
#include <stdint.h>

namespace cg = cooperative_groups;

// Problem dims
#define M_DIM 8000
#define K_DIM 120
#define N_DIM 8000
#define M_PADD 8064   // padded M for Abf
#define N_PADB 8192   // padded N for Bbf (pow2 for cheap div in conv)
#define K_PADD 128

#define CONV_A_UNITS 504   // 8064*16/256
#define CONV_B_UNITS 512   // 8192*16/256
#define CONV_UNITS   (CONV_A_UNITS + CONV_B_UNITS)   // 1016
#define TILES_N 63
#define TILES_M 126
#define N_TILES (TILES_N * TILES_M)                  // 7938
#define COOP_BLOCKS 768    // 256 CUs x 3 blocks/CU (48KB LDS, lb(256,3))

typedef __attribute__((ext_vector_type(8))) __bf16 bf16x8;
typedef __attribute__((ext_vector_type(4))) float f32x4;
typedef __attribute__((ext_vector_type(8))) unsigned short u16x8;

__device__ __forceinline__ unsigned short f2bf(float f) {
  unsigned int u = __builtin_bit_cast(unsigned int, f);
  u += 0x7FFFu + ((u >> 16) & 1u);   // round-to-nearest-even
  return (unsigned short)(u >> 16);
}

// One 256-thread conv work unit (same math as the proven standalone conv).
// Abf [8064][128] bf16 zero-padded, row-swizzled: (row,k) at byte
//   row*256 + ((2k) ^ ((row&7)<<4)).  Bbf [8192][128] = B^T, same swizzle.
__device__ __forceinline__ void conv_unit(int u, int tid,
                                          const float* __restrict__ A,
                                          const float* __restrict__ B,
                                          unsigned short* __restrict__ Abf,
                                          unsigned short* __restrict__ Bbf) {
  if (u < CONV_A_UNITS) {
    int t = u * 256 + tid;
    int row = t >> 4;     // 0..8063
    int kg  = t & 15;     // k-group of 8 elems
    u16x8 v = (u16x8)0;
    if (row < M_DIM && kg < 15) {   // kg=14 covers k=112..119; kg=15 is pad
      const float* src = A + (size_t)row * K_DIM + kg * 8;  // 32B-aligned
      float4 f0 = *(const float4*)(src);
      float4 f1 = *(const float4*)(src + 4);
      v[0] = f2bf(f0.x); v[1] = f2bf(f0.y); v[2] = f2bf(f0.z); v[3] = f2bf(f0.w);
      v[4] = f2bf(f1.x); v[5] = f2bf(f1.y); v[6] = f2bf(f1.z); v[7] = f2bf(f1.w);
    }
    int off = (kg * 16) ^ ((row & 7) << 4);
    *(u16x8*)((char*)Abf + (size_t)row * 256 + off) = v;
  } else {
    int t = (u - CONV_A_UNITS) * 256 + tid;
    int kg = t >> 13;         // 0..15  (N_PADB = 8192)
    int n  = t & (N_PADB - 1);
    u16x8 v = (u16x8)0;
    if (n < N_DIM && kg < 15) {
      const float* src = B + (size_t)(kg * 8) * N_DIM + n;
#pragma unroll
      for (int j = 0; j < 8; ++j) v[j] = f2bf(src[(size_t)j * N_DIM]);
    }
    int off = (kg * 16) ^ ((n & 7) << 4);
    *(u16x8*)((char*)Bbf + (size_t)n * 256 + off) = v;
  }
}

// One 64x128 output tile (byte-identical to the R6 proven body).
// smem: As [0,16K), Bs [16K,48K); tbuf [64][132] f32 overlays.
__device__ __forceinline__ void gemm_tile(int bn, int bm, int tid, char* smem,
                                          const unsigned short* __restrict__ Abf,
                                          const unsigned short* __restrict__ Bbf,
                                          const float* __restrict__ bias,
                                          float* __restrict__ out) {
  const int lane = tid & 63;
  const int wave = tid >> 6;   // 0..3 == column slot (32 cols each)
  const int l15 = lane & 15;
  const int kq  = lane >> 4;   // 0..3

  const char* gA = (const char*)Abf + (size_t)bm * 16384;
  const char* gB = (const char*)Bbf + (size_t)bn * 32768;
#pragma unroll
  for (int i = 0; i < 4; ++i) {
    int off = i * 4096 + tid * 16;
    __builtin_amdgcn_global_load_lds(
        (const __attribute__((address_space(1))) void*)(gA + off),
        (__attribute__((address_space(3))) void*)(smem + off), 16, 0, 0);
  }
#pragma unroll
  for (int i = 0; i < 8; ++i) {
    int off = i * 4096 + tid * 16;
    __builtin_amdgcn_global_load_lds(
        (const __attribute__((address_space(1))) void*)(gB + off),
        (__attribute__((address_space(3))) void*)(smem + 16384 + off), 16, 0, 0);
  }
  __syncthreads();   // drains vmcnt before barrier

  f32x4 acc[4][2] = {};
#pragma unroll
  for (int ks = 0; ks < 4; ++ks) {
    const int kb = (ks * 32 + kq * 8) * 2;
    bf16x8 a[4], b[2];
#pragma unroll
    for (int m = 0; m < 4; ++m) {
      int row = m * 16 + l15;
      a[m] = *(const bf16x8*)(smem + (size_t)row * 256 + (kb ^ ((row & 7) << 4)));
    }
#pragma unroll
    for (int n = 0; n < 2; ++n) {
      int row = wave * 32 + n * 16 + l15;
      b[n] = *(const bf16x8*)(smem + 16384 + (size_t)row * 256 + (kb ^ ((row & 7) << 4)));
    }
#pragma unroll
    for (int m = 0; m < 4; ++m)
#pragma unroll
      for (int n = 0; n < 2; ++n)
        acc[m][n] = __builtin_amdgcn_mfma_f32_16x16x32_bf16(a[m], b[n], acc[m][n], 0, 0, 0);
  }

  // C/D layout: col = lane&15, row_in_16 = (lane>>4)*4 + reg  [m89-verified]
  float bv[2];
#pragma unroll
  for (int n = 0; n < 2; ++n) {
    int gcol = bn * 128 + wave * 32 + n * 16 + l15;
    bv[n] = (gcol < N_DIM) ? bias[gcol] : 0.f;
  }

  float* tbuf = (float*)smem;
  __syncthreads();                 // all compute reads of As/Bs done
#pragma unroll
  for (int m = 0; m < 4; ++m)
#pragma unroll
    for (int n = 0; n < 2; ++n)
#pragma unroll
      for (int r = 0; r < 4; ++r) {
        int rl = m * 16 + kq * 4 + r;          // 0..63
        int c  = wave * 32 + n * 16 + l15;     // 0..127
        tbuf[rl * 132 + c] = acc[m][n][r] + bv[n];
      }
  __syncthreads();

  const int c = lane & 31;
  const int gcol0 = bn * 128 + c * 4;
  const bool colok = (gcol0 < N_DIM);
#pragma unroll
  for (int j = 0; j < 8; ++j) {
    int row = j * 8 + wave * 2 + (lane >> 5);  // 0..63
    f32x4 v = *(const f32x4*)(tbuf + row * 132 + c * 4);
    if (colok) {
      size_t off = (size_t)(bm * 64 + row) * N_DIM + gcol0;
      __builtin_nontemporal_store(v, (f32x4*)(out + off));
    }
  }
}

// ---- Cooperative fused kernel: conv phase -> grid.sync -> gemm phase ----
__global__ __launch_bounds__(256, 3) void fused_kernel(const float* __restrict__ A,
                                                       const float* __restrict__ B,
                                                       const float* __restrict__ bias,
                                                       unsigned short* __restrict__ Abf,
                                                       unsigned short* __restrict__ Bbf,
                                                       float* __restrict__ out) {
  __shared__ __align__(16) char smem[49152];
  const int bid = blockIdx.x;
  const int tid = threadIdx.x;

  for (int u = bid; u < CONV_UNITS; u += COOP_BLOCKS)
    conv_unit(u, tid, A, B, Abf, Bbf);

  __threadfence();               // release: write back dirty L2 (cross-XCD)
  cg::this_grid().sync();
  __threadfence();               // acquire: invalidate stale lines

  for (int t = bid; t < N_TILES; t += COOP_BLOCKS) {
    int bn = t % TILES_N;
    int bm = t / TILES_N;
    gemm_tile(bn, bm, tid, smem, Abf, Bbf, bias, out);
    __syncthreads();             // tbuf reads done before next tile's staging
  }
}

// ---- Classic two-kernel fallback (exact R6 structure) ----
__global__ __launch_bounds__(256) void conv_ab_kernel(const float* __restrict__ A,
                                                      const float* __restrict__ B,
                                                      unsigned short* __restrict__ Abf,
                                                      unsigned short* __restrict__ Bbf) {
  conv_unit(blockIdx.x, threadIdx.x, A, B, Abf, Bbf);
}

__global__ __launch_bounds__(256, 3) void gemm_bias_kernel(const unsigned short* __restrict__ Abf,
                                                           const unsigned short* __restrict__ Bbf,
                                                           const float* __restrict__ bias,
                                                           float* __restrict__ out) {
  __shared__ __align__(16) char smem[49152];
  gemm_tile(blockIdx.x, blockIdx.y, threadIdx.x, smem, Abf, Bbf, bias, out);
}

// Safety net if ws_size is too small for the bf16 staging buffers.
__global__ __launch_bounds__(256) void fallback_kernel(const float* __restrict__ A,
                                                       const float* __restrict__ B,
                                                       const float* __restrict__ bias,
                                                       float* __restrict__ out) {
  size_t idx = (size_t)blockIdx.x * 256 + threadIdx.x;
  if (idx >= (size_t)M_PADD * N_DIM) return;
  int col = (int)(idx % N_DIM);
  int row = (int)(idx / N_DIM);
  float s = 0.f;
  if (row < M_DIM) {
    for (int k = 0; k < K_DIM; ++k)
      s += A[(size_t)row * K_DIM + k] * B[(size_t)k * N_DIM + col];
  }
  out[idx] = s + bias[col];
}

extern "C" void kernel_launch(void* const* d_in, const int* in_sizes, int n_in,
                              void* d_out, int out_size, void* d_ws, size_t ws_size,
                              hipStream_t stream) {
  const float* A    = (const float*)d_in[0];
  const float* Bm   = (const float*)d_in[1];
  const float* bias = (const float*)d_in[2];
  float* out = (float*)d_out;

  const size_t abf_elems = (size_t)M_PADD * K_PADD;   // 1,032,192
  const size_t bbf_elems = (size_t)N_PADB * K_PADD;   // 1,048,576
  const size_t need = (abf_elems + bbf_elems) * sizeof(unsigned short);  // ~4.16 MB
  if (ws_size < need) {
    size_t total = (size_t)M_PADD * N_DIM;
    fallback_kernel<<<dim3((unsigned)((total + 255) / 256)), dim3(256), 0, stream>>>(A, Bm, bias, out);
    return;
  }

  unsigned short* Abf = (unsigned short*)d_ws;
  unsigned short* Bbf = Abf + abf_elems;   // 16B-aligned offset

  void* args[] = {(void*)&A, (void*)&Bm, (void*)&bias,
                  (void*)&Abf, (void*)&Bbf, (void*)&out};
  hipError_t e = hipLaunchCooperativeKernel((const void*)fused_kernel,
                                            dim3(COOP_BLOCKS), dim3(256),
                                            args, 0, stream);
  if (e != hipSuccess) {
    // Fallback: exact two-kernel path (identical output).
    conv_ab_kernel<<<dim3(CONV_UNITS), dim3(256), 0, stream>>>(A, Bm, Abf, Bbf);
    gemm_bias_kernel<<<dim3(TILES_N, TILES_M), dim3(256), 0, stream>>>(Abf, Bbf, bias, out);
  }
}

// Round 11
// 58.042 us; speedup vs baseline: 5.2615x; 5.2615x over previous
//
#include <hip/hip_runtime.h>
#include <hip/hip_bf16.h>
#include <stdint.h>

// Problem dims
#define M_DIM 8000
#define K_DIM 120
#define N_DIM 8000
#define M_PADD 8064   // padded M (126 x 64-row tiles)
#define N_PADB 8064   // padded N (63 x 128-col tiles)
#define K_PADD 128

typedef __attribute__((ext_vector_type(8))) __bf16 bf16x8;
typedef __attribute__((ext_vector_type(4))) float f32x4;
typedef __attribute__((ext_vector_type(8))) unsigned short u16x8;

__device__ __forceinline__ unsigned short f2bf(float f) {
  unsigned int u = __builtin_bit_cast(unsigned int, f);
  u += 0x7FFFu + ((u >> 16) & 1u);   // round-to-nearest-even
  return (unsigned short)(u >> 16);
}

#define CONV_A_BLOCKS 504   // 8064*16/256
#define CONV_B_BLOCKS 504   // 8064*16/256

// Fragment-interleaved workspace layout (the key change vs R6):
// 16B chunk index for element-group (x, kg)  [x = A-row or B^T-row n]:
//   chunk16(x,kg) = (x>>4)*256 + (kg>>2)*64 + (kg&3)*16 + (x&15)
// With lane = kq*16+l15, a wave's MFMA fragment load for (tile, m|n, ks) is
//   base + lane*16  -> one fully coalesced 1KB global_load_dwordx4 burst.
__global__ __launch_bounds__(256) void conv_ab_kernel(const float* __restrict__ A,
                                                      const float* __restrict__ B,
                                                      unsigned short* __restrict__ Af,
                                                      unsigned short* __restrict__ Bf) {
  const int bid = blockIdx.x;
  if (bid < CONV_A_BLOCKS) {
    int t = bid * 256 + threadIdx.x;
    int row = t >> 4;     // 0..8063
    int kg  = t & 15;     // k-group of 8 elems
    u16x8 v = (u16x8)0;
    if (row < M_DIM && kg < 15) {   // kg=14 covers k=112..119; kg=15 is pad
      const float* src = A + (size_t)row * K_DIM + kg * 8;  // 32B-aligned (480%32==0)
      float4 f0 = *(const float4*)(src);
      float4 f1 = *(const float4*)(src + 4);
      v[0] = f2bf(f0.x); v[1] = f2bf(f0.y); v[2] = f2bf(f0.z); v[3] = f2bf(f0.w);
      v[4] = f2bf(f1.x); v[5] = f2bf(f1.y); v[6] = f2bf(f1.z); v[7] = f2bf(f1.w);
    }
    int c16 = (row >> 4) * 256 + (kg >> 2) * 64 + (kg & 3) * 16 + (row & 15);
    *(u16x8*)((char*)Af + (size_t)c16 * 16) = v;
  } else {
    int t = (bid - CONV_A_BLOCKS) * 256 + threadIdx.x;
    int kg = t / N_PADB;  // 0..15 (consecutive tid -> consecutive n: coalesced reads)
    int n  = t % N_PADB;  // 0..8063
    u16x8 v = (u16x8)0;
    if (n < N_DIM && kg < 15) {
      const float* src = B + (size_t)(kg * 8) * N_DIM + n;
#pragma unroll
      for (int j = 0; j < 8; ++j) v[j] = f2bf(src[(size_t)j * N_DIM]);
    }
    int c16 = (n >> 4) * 256 + (kg >> 2) * 64 + (kg & 3) * 16 + (n & 15);
    *(u16x8*)((char*)Bf + (size_t)c16 * 16) = v;
  }
}

// 64x128 output tile per block, 4 waves, single K-tile (K=128).
// NO input staging: MFMA fragments load directly from the fragment-interleaved
// workspace (coalesced 1KB/wave bursts, L2-resident). No barriers before the
// epilogue; loads pipeline against MFMA. LDS holds only the 33.8KB transpose
// buffer. NT stores (R7: removing them cost 13us).
__global__ __launch_bounds__(256, 3) void gemm_bias_kernel(const unsigned short* __restrict__ Af,
                                                           const unsigned short* __restrict__ Bf,
                                                           const float* __restrict__ bias,
                                                           float* __restrict__ out) {
  __shared__ __align__(16) float tbuf[64 * 132];   // 33.8 KB
  const int bn = blockIdx.x;   // 0..62  (128-col tiles)
  const int bm = blockIdx.y;   // 0..125 (64-row tiles)
  const int tid  = threadIdx.x;
  const int lane = tid & 63;
  const int wave = tid >> 6;   // 0..3 == 32-col slot
  const int l15 = lane & 15;
  const int kq  = lane >> 4;   // 0..3

  // Fragment group bases: A group (bm,m,ks) at ((bm*4+m)*4+ks)*1024 bytes;
  // B group (bn,wave,nn,ks) at (((bn*8+wave*2+nn)*4)+ks)*1024 bytes.
  const char* aBase = (const char*)Af + (size_t)(bm * 16) * 1024 + lane * 16;
  const char* bBase = (const char*)Bf + (size_t)((bn * 8 + wave * 2) * 4) * 1024 + lane * 16;

  f32x4 acc[4][2] = {};
#pragma unroll
  for (int ks = 0; ks < 4; ++ks) {
    bf16x8 a[4], b[2];
#pragma unroll
    for (int m = 0; m < 4; ++m)
      a[m] = *(const bf16x8*)(aBase + (m * 4 + ks) * 1024);
#pragma unroll
    for (int n = 0; n < 2; ++n)
      b[n] = *(const bf16x8*)(bBase + (n * 4 + ks) * 1024);
#pragma unroll
    for (int m = 0; m < 4; ++m)
#pragma unroll
      for (int n = 0; n < 2; ++n)
        acc[m][n] = __builtin_amdgcn_mfma_f32_16x16x32_bf16(a[m], b[n], acc[m][n], 0, 0, 0);
  }

  // ---- Epilogue ----
  // C/D layout: col = lane&15, row_in_16 = (lane>>4)*4 + reg   [m89-verified]
  float bv[2];
#pragma unroll
  for (int n = 0; n < 2; ++n) {
    int gcol = bn * 128 + wave * 32 + n * 16 + l15;
    bv[n] = (gcol < N_DIM) ? bias[gcol] : 0.f;
  }

#pragma unroll
  for (int m = 0; m < 4; ++m)
#pragma unroll
    for (int n = 0; n < 2; ++n)
#pragma unroll
      for (int r = 0; r < 4; ++r) {
        int rl = m * 16 + kq * 4 + r;          // 0..63
        int c  = wave * 32 + n * 16 + l15;     // 0..127
        tbuf[rl * 132 + c] = acc[m][n][r] + bv[n];
      }
  __syncthreads();

  // Stream out: each wave instr covers 2 rows x 512B contiguous. NT stores.
  const int c = lane & 31;                     // 16-B chunk within row
  const int gcol0 = bn * 128 + c * 4;
  const bool colok = (gcol0 < N_DIM);          // chunk fully valid (8000%4==0)
#pragma unroll
  for (int j = 0; j < 8; ++j) {
    int row = j * 8 + wave * 2 + (lane >> 5);  // 0..63
    f32x4 v = *(const f32x4*)(tbuf + row * 132 + c * 4);
    if (colok) {
      size_t off = (size_t)(bm * 64 + row) * N_DIM + gcol0;
      __builtin_nontemporal_store(v, (f32x4*)(out + off));
    }
  }
}

// Safety net if ws_size is too small for the bf16 staging buffers.
__global__ __launch_bounds__(256) void fallback_kernel(const float* __restrict__ A,
                                                       const float* __restrict__ B,
                                                       const float* __restrict__ bias,
                                                       float* __restrict__ out) {
  size_t idx = (size_t)blockIdx.x * 256 + threadIdx.x;
  if (idx >= (size_t)M_PADD * N_DIM) return;
  int col = (int)(idx % N_DIM);
  int row = (int)(idx / N_DIM);
  float s = 0.f;
  if (row < M_DIM) {
    for (int k = 0; k < K_DIM; ++k)
      s += A[(size_t)row * K_DIM + k] * B[(size_t)k * N_DIM + col];
  }
  out[idx] = s + bias[col];
}

extern "C" void kernel_launch(void* const* d_in, const int* in_sizes, int n_in,
                              void* d_out, int out_size, void* d_ws, size_t ws_size,
                              hipStream_t stream) {
  const float* A    = (const float*)d_in[0];
  const float* Bm   = (const float*)d_in[1];
  const float* bias = (const float*)d_in[2];
  float* out = (float*)d_out;

  const size_t af_elems = (size_t)M_PADD * K_PADD;   // 1,032,192
  const size_t bf_elems = (size_t)N_PADB * K_PADD;   // 1,032,192
  const size_t need = (af_elems + bf_elems) * sizeof(unsigned short);  // ~4.13 MB
  if (ws_size < need) {
    size_t total = (size_t)M_PADD * N_DIM;
    fallback_kernel<<<dim3((unsigned)((total + 255) / 256)), dim3(256), 0, stream>>>(A, Bm, bias, out);
    return;
  }

  unsigned short* Af = (unsigned short*)d_ws;
  unsigned short* Bf = Af + af_elems;   // 16B-aligned offset

  conv_ab_kernel<<<dim3(CONV_A_BLOCKS + CONV_B_BLOCKS), dim3(256), 0, stream>>>(A, Bm, Af, Bf);
  gemm_bias_kernel<<<dim3(63, 126), dim3(256), 0, stream>>>(Af, Bf, bias, out);
}